// Round 3
// baseline (1606.470 us; speedup 1.0000x reference)
//
#include <hip/hip_runtime.h>

#define RES   1024
#define NPTS  200000
#define NB    32

// ---------------------------------------------------------------------------
// Pass 2: per-point scatter. winner[pixel] = max point-index n (atomicMax).
// Dot products replicate numpy einsum baseline-SIMD semantics for k=4:
// separately-rounded products, pairwise (SSE3 hadd) association:
//   t = (x*M0 + y*M1) + (z*M2 + M3)
// fp contract OFF so hipcc can't fuse into FMA.
// ---------------------------------------------------------------------------
__global__ __launch_bounds__(256) void pc2depth_scatter(
        const float* __restrict__ pc,   // (B, N, 3)
        const float* __restrict__ tm,   // (B, 3, 4)
        int* __restrict__ win)          // (B, RES, RES) init -1
{
#pragma clang fp contract(off)
    int i = blockIdx.x * blockDim.x + threadIdx.x;
    if (i >= NB * NPTS) return;
    int b = i / NPTS;
    int n = i - b * NPTS;

    const float* p = pc + (size_t)i * 3;
    float x = p[0], y = p[1], z = p[2];

    const float* M = tm + b * 12;

    // row 0: pairwise association of separately-rounded products
    float tx = (x * M[0] + y * M[1]) + (z * M[2] + M[3]);
    // row 1
    float ty = (x * M[4] + y * M[5]) + (z * M[6] + M[7]);

    // normalized = t / 2 (exact pow2); px = (nx+1)/2*R == (nx+1)*512 (exact)
    float nx = tx * 0.5f;
    float ny = ty * 0.5f;
    float px = (nx + 1.0f) * 512.0f;
    float py = (1.0f - ny) * 512.0f;
    px = fminf(fmaxf(px, 0.0f), 1023.0f);
    py = fminf(fmaxf(py, 0.0f), 1023.0f);
    int xi = (int)floorf(px);
    int yi = (int)floorf(py);

    atomicMax(&win[(size_t)b * (RES * RES) + (size_t)yi * RES + xi], n);
}

// ---------------------------------------------------------------------------
// Pass 3: per-pixel resolve. out = z(winner) or 0. 4 pixels/thread.
// ---------------------------------------------------------------------------
__device__ __forceinline__ float resolve_one(int w, int b,
                                             const float* __restrict__ pc,
                                             const float* __restrict__ M2)
{
#pragma clang fp contract(off)
    if (w < 0) return 0.0f;
    const float* p = pc + ((size_t)b * NPTS + (size_t)w) * 3;
    float t = (p[0] * M2[0] + p[1] * M2[1]) + (p[2] * M2[2] + M2[3]);
    return t * 0.5f;   // normalized z = transformed / DEPTH
}

__global__ __launch_bounds__(256) void pc2depth_resolve(
        const int* __restrict__ win,
        const float* __restrict__ pc,
        const float* __restrict__ tm,
        float* __restrict__ out)
{
    size_t g = (size_t)blockIdx.x * blockDim.x + threadIdx.x; // group of 4 px
    // groups per batch = RES*RES/4 = 262144 = 2^18
    int b = (int)(g >> 18);
    const float* M2 = tm + b * 12 + 8;  // row 2 of 3x4

    int4 w4 = ((const int4*)win)[g];
    float4 o;
    o.x = resolve_one(w4.x, b, pc, M2);
    o.y = resolve_one(w4.y, b, pc, M2);
    o.z = resolve_one(w4.z, b, pc, M2);
    o.w = resolve_one(w4.w, b, pc, M2);
    ((float4*)out)[g] = o;
}

// ---------------------------------------------------------------------------
extern "C" void kernel_launch(void* const* d_in, const int* in_sizes, int n_in,
                              void* d_out, int out_size, void* d_ws, size_t ws_size,
                              hipStream_t stream)
{
    const float* pc = (const float*)d_in[0];   // (32, 200000, 3) f32
    const float* tm = (const float*)d_in[1];   // (32, 3, 4) f32
    float* out = (float*)d_out;                // (32, 1024, 1024) f32
    int* win = (int*)d_ws;                     // (32, 1024, 1024) i32

    const size_t npix = (size_t)NB * RES * RES;           // 33,554,432
    hipMemsetAsync(win, 0xFF, npix * sizeof(int), stream); // all -1

    const int npoints = NB * NPTS;                         // 6,400,000
    pc2depth_scatter<<<(npoints + 255) / 256, 256, 0, stream>>>(pc, tm, win);

    const int ngroups = (int)(npix / 4);                   // 8,388,608
    pc2depth_resolve<<<ngroups / 256, 256, 0, stream>>>(win, pc, tm, out);
}

// Round 4
// 550.385 us; speedup vs baseline: 2.9188x; 2.9188x over previous
//
#include <hip/hip_runtime.h>

#define RES   1024
#define NPTS  200000
#define NB    32
#define PPT   8          // points per thread
#define BLK   256

// ---------------------------------------------------------------------------
// Scatter: winner[pixel] = max point-index n (atomicMax), with corner-pixel
// privatization (the 4 clipped corners receive thousands of same-address
// atomics -> serialize; accumulate them in registers/LDS, flush 4 per block).
// Dot product replicates numpy einsum k=4 semantics: separately-rounded
// products, pairwise association. fp contract OFF.
// ---------------------------------------------------------------------------
__global__ __launch_bounds__(BLK) void pc2depth_scatter(
        const float* __restrict__ pc,   // (B, N, 3)
        const float* __restrict__ tm,   // (B, 3, 4)
        int* __restrict__ win)          // (B, RES, RES) init -1
{
#pragma clang fp contract(off)
    const int b   = blockIdx.y;
    const int tid = threadIdx.x;

    __shared__ int lcorner[4];
    if (tid < 4) lcorner[tid] = -1;
    __syncthreads();

    const float* M = tm + b * 12;
    const float m0 = M[0], m1 = M[1], m2 = M[2], m3 = M[3];
    const float m4 = M[4], m5 = M[5], m6 = M[6], m7 = M[7];

    int* const winb = win + (size_t)b * (RES * RES);

    // corner maxima: j = (yi==1023)*2 + (xi==1023)
    int c0 = -1, c1 = -1, c2 = -1, c3 = -1;

    const int base = blockIdx.x * (BLK * PPT) + tid;
    #pragma unroll
    for (int k = 0; k < PPT; ++k) {
        int n = base + k * BLK;
        if (n >= NPTS) break;
        const float* p = pc + ((size_t)b * NPTS + n) * 3;
        float x = p[0], y = p[1], z = p[2];

        // pairwise association of separately-rounded products (numpy einsum)
        float tx = (x * m0 + y * m1) + (z * m2 + m3);
        float ty = (x * m4 + y * m5) + (z * m6 + m7);

        float nx = tx * 0.5f;
        float ny = ty * 0.5f;
        float px = (nx + 1.0f) * 512.0f;
        float py = (1.0f - ny) * 512.0f;
        px = fminf(fmaxf(px, 0.0f), 1023.0f);
        py = fminf(fmaxf(py, 0.0f), 1023.0f);
        int xi = (int)floorf(px);
        int yi = (int)floorf(py);

        bool cx = (xi == 0) | (xi == 1023);
        bool cy = (yi == 0) | (yi == 1023);
        if (cx & cy) {
            int j = ((yi == 1023) ? 2 : 0) + ((xi == 1023) ? 1 : 0);
            // n is monotonically increasing within the loop; max keeps safety
            if (j == 0) c0 = max(c0, n);
            else if (j == 1) c1 = max(c1, n);
            else if (j == 2) c2 = max(c2, n);
            else c3 = max(c3, n);
        } else {
            atomicMax(&winb[yi * RES + xi], n);
        }
    }

    // wave-level reduce the 4 corner maxima (64-lane butterfly)
    #pragma unroll
    for (int off = 32; off > 0; off >>= 1) {
        c0 = max(c0, __shfl_xor(c0, off));
        c1 = max(c1, __shfl_xor(c1, off));
        c2 = max(c2, __shfl_xor(c2, off));
        c3 = max(c3, __shfl_xor(c3, off));
    }
    if ((tid & 63) == 0) {
        if (c0 >= 0) atomicMax(&lcorner[0], c0);
        if (c1 >= 0) atomicMax(&lcorner[1], c1);
        if (c2 >= 0) atomicMax(&lcorner[2], c2);
        if (c3 >= 0) atomicMax(&lcorner[3], c3);
    }
    __syncthreads();
    if (tid < 4) {
        int v = lcorner[tid];
        if (v >= 0) {
            int xi = (tid & 1) ? 1023 : 0;
            int yi = (tid & 2) ? 1023 : 0;
            atomicMax(&winb[yi * RES + xi], v);
        }
    }
}

// ---------------------------------------------------------------------------
// Resolve: out = z(winner) or 0. 4 pixels/thread.
// ---------------------------------------------------------------------------
__device__ __forceinline__ float resolve_one(int w, int b,
                                             const float* __restrict__ pc,
                                             const float* __restrict__ M2)
{
#pragma clang fp contract(off)
    if (w < 0) return 0.0f;
    const float* p = pc + ((size_t)b * NPTS + (size_t)w) * 3;
    float t = (p[0] * M2[0] + p[1] * M2[1]) + (p[2] * M2[2] + M2[3]);
    return t * 0.5f;   // normalized z = transformed / DEPTH
}

__global__ __launch_bounds__(256) void pc2depth_resolve(
        const int* __restrict__ win,
        const float* __restrict__ pc,
        const float* __restrict__ tm,
        float* __restrict__ out)
{
    size_t g = (size_t)blockIdx.x * blockDim.x + threadIdx.x; // group of 4 px
    int b = (int)(g >> 18);                                   // RES*RES/4 = 2^18
    const float* M2 = tm + b * 12 + 8;

    int4 w4 = ((const int4*)win)[g];
    float4 o;
    o.x = resolve_one(w4.x, b, pc, M2);
    o.y = resolve_one(w4.y, b, pc, M2);
    o.z = resolve_one(w4.z, b, pc, M2);
    o.w = resolve_one(w4.w, b, pc, M2);
    ((float4*)out)[g] = o;
}

// ---------------------------------------------------------------------------
extern "C" void kernel_launch(void* const* d_in, const int* in_sizes, int n_in,
                              void* d_out, int out_size, void* d_ws, size_t ws_size,
                              hipStream_t stream)
{
    const float* pc = (const float*)d_in[0];   // (32, 200000, 3) f32
    const float* tm = (const float*)d_in[1];   // (32, 3, 4) f32
    float* out = (float*)d_out;                // (32, 1024, 1024) f32
    int* win = (int*)d_ws;                     // (32, 1024, 1024) i32

    const size_t npix = (size_t)NB * RES * RES;            // 33,554,432
    hipMemsetAsync(win, 0xFF, npix * sizeof(int), stream); // all -1

    dim3 sgrid((NPTS + BLK * PPT - 1) / (BLK * PPT), NB);  // (98, 32)
    pc2depth_scatter<<<sgrid, BLK, 0, stream>>>(pc, tm, win);

    const int ngroups = (int)(npix / 4);                   // 8,388,608
    pc2depth_resolve<<<ngroups / 256, 256, 0, stream>>>(win, pc, tm, out);
}

// Round 5
// 296.714 us; speedup vs baseline: 5.4142x; 1.8549x over previous
//
#include <hip/hip_runtime.h>

#define RES   1024
#define NPTS  200000
#define NB    32
#define PPT   16         // points per thread
#define BLK   256
#define BORD  4096       // 4*1024 border pixels, privatized in LDS

// ---------------------------------------------------------------------------
// Scatter: winner[pixel] = max point-index n (atomicMax).
// All clipped (border) pixels are privatized per-block in a 4096-entry LDS
// array — single-axis-clipped points can collapse ~40% of a batch into one
// border row/column (same-line RMW storms); LDS absorbs them at ~cycle cost,
// then each block flushes non-empty entries once.
// Dot product replicates numpy einsum k=4 semantics: separately-rounded
// products, pairwise association. fp contract OFF.
// ---------------------------------------------------------------------------
__global__ __launch_bounds__(BLK) void pc2depth_scatter(
        const float* __restrict__ pc,   // (B, N, 3)
        const float* __restrict__ tm,   // (B, 3, 4)
        int* __restrict__ win)          // (B, RES, RES) init -1
{
#pragma clang fp contract(off)
    const int b   = blockIdx.y;
    const int tid = threadIdx.x;

    __shared__ int sb[BORD];
    #pragma unroll
    for (int k = tid; k < BORD; k += BLK) sb[k] = -1;
    __syncthreads();

    const float* M = tm + b * 12;
    const float m0 = M[0], m1 = M[1], m2 = M[2], m3 = M[3];
    const float m4 = M[4], m5 = M[5], m6 = M[6], m7 = M[7];

    int* const winb = win + (size_t)b * (RES * RES);

    const int base = blockIdx.x * (BLK * PPT) + tid;
    #pragma unroll
    for (int k = 0; k < PPT; ++k) {
        int n = base + k * BLK;
        if (n >= NPTS) break;
        const float* p = pc + ((size_t)b * NPTS + n) * 3;
        float x = p[0], y = p[1], z = p[2];

        // pairwise association of separately-rounded products (numpy einsum)
        float tx = (x * m0 + y * m1) + (z * m2 + m3);
        float ty = (x * m4 + y * m5) + (z * m6 + m7);

        float nx = tx * 0.5f;
        float ny = ty * 0.5f;
        float px = (nx + 1.0f) * 512.0f;
        float py = (1.0f - ny) * 512.0f;
        px = fminf(fmaxf(px, 0.0f), 1023.0f);
        py = fminf(fmaxf(py, 0.0f), 1023.0f);
        int xi = (int)floorf(px);
        int yi = (int)floorf(py);

        bool border = (xi == 0) | (xi == 1023) | (yi == 0) | (yi == 1023);
        if (border) {
            // unique mapping; y-rows take precedence at corners
            int idx = (yi == 0)    ? xi
                    : (yi == 1023) ? 1024 + xi
                    : (xi == 0)    ? 2048 + yi
                                   : 3072 + yi;
            atomicMax(&sb[idx], n);
        } else {
            atomicMax(&winb[yi * RES + xi], n);
        }
    }

    __syncthreads();
    // flush non-empty border entries (<=1 global atomic per entry per block)
    #pragma unroll
    for (int k = tid; k < BORD; k += BLK) {
        int v = sb[k];
        if (v >= 0) {
            int xi, yi;
            if      (k < 1024) { xi = k;        yi = 0;    }
            else if (k < 2048) { xi = k - 1024; yi = 1023; }
            else if (k < 3072) { xi = 0;        yi = k - 2048; }
            else               { xi = 1023;     yi = k - 3072; }
            atomicMax(&winb[yi * RES + xi], v);
        }
    }
}

// ---------------------------------------------------------------------------
// Resolve: out = z(winner) or 0. 4 pixels/thread.
// ---------------------------------------------------------------------------
__device__ __forceinline__ float resolve_one(int w, int b,
                                             const float* __restrict__ pc,
                                             const float* __restrict__ M2)
{
#pragma clang fp contract(off)
    if (w < 0) return 0.0f;
    const float* p = pc + ((size_t)b * NPTS + (size_t)w) * 3;
    float t = (p[0] * M2[0] + p[1] * M2[1]) + (p[2] * M2[2] + M2[3]);
    return t * 0.5f;   // normalized z = transformed / DEPTH
}

__global__ __launch_bounds__(256) void pc2depth_resolve(
        const int* __restrict__ win,
        const float* __restrict__ pc,
        const float* __restrict__ tm,
        float* __restrict__ out)
{
    size_t g = (size_t)blockIdx.x * blockDim.x + threadIdx.x; // group of 4 px
    int b = (int)(g >> 18);                                   // RES*RES/4 = 2^18
    const float* M2 = tm + b * 12 + 8;

    int4 w4 = ((const int4*)win)[g];
    float4 o;
    o.x = resolve_one(w4.x, b, pc, M2);
    o.y = resolve_one(w4.y, b, pc, M2);
    o.z = resolve_one(w4.z, b, pc, M2);
    o.w = resolve_one(w4.w, b, pc, M2);
    ((float4*)out)[g] = o;
}

// ---------------------------------------------------------------------------
extern "C" void kernel_launch(void* const* d_in, const int* in_sizes, int n_in,
                              void* d_out, int out_size, void* d_ws, size_t ws_size,
                              hipStream_t stream)
{
    const float* pc = (const float*)d_in[0];   // (32, 200000, 3) f32
    const float* tm = (const float*)d_in[1];   // (32, 3, 4) f32
    float* out = (float*)d_out;                // (32, 1024, 1024) f32
    int* win = (int*)d_ws;                     // (32, 1024, 1024) i32

    const size_t npix = (size_t)NB * RES * RES;            // 33,554,432
    hipMemsetAsync(win, 0xFF, npix * sizeof(int), stream); // all -1

    dim3 sgrid((NPTS + BLK * PPT - 1) / (BLK * PPT), NB);  // (49, 32)
    pc2depth_scatter<<<sgrid, BLK, 0, stream>>>(pc, tm, win);

    const int ngroups = (int)(npix / 4);                   // 8,388,608
    pc2depth_resolve<<<ngroups / 256, 256, 0, stream>>>(win, pc, tm, out);
}

// Round 6
// 125.267 us; speedup vs baseline: 12.8244x; 2.3687x over previous
//
#include <hip/hip_runtime.h>

#define RES   1024
#define NPTS  200000
#define NB    32
#define PPT   16
#define BLK   256
#define NBLK  49          // blocks per batch = ceil(200000/4096)
#define BPB   (BLK*PPT)   // 4096 points per block
#define NBAND 64          // 64 bands of 16 rows per batch
#define BANDH 16
#define BORD  4096        // 4*1024 border pixels

// ws layout (all offsets 4096-aligned):
//  arena : NB*NBLK*BPB u32        = 25,690,112 B
//  toff  : NB*NBLK*NBAND u32      =    401,408 B
//  tcnt  : NB*NBLK*NBAND u32      =    401,408 B
//  sbdump: NB*NBLK*BORD i32       = 25,690,112 B
//  bwin  : NB*BORD i32            =    524,288 B
#define OFF_AR 0
#define OFF_TO 25690112
#define OFF_TC 26091520
#define OFF_SB 26492928
#define OFF_BW 52183040

// ---------------------------------------------------------------------------
// Pass 1: bin points. Interior -> banded arena (LDS hist + wave scan, DS
// atomics only). Border pixels -> LDS sb[4096] (round-5 technique), dumped
// coalesced (no contended global flush). ZERO global atomics.
// Dot product replicates numpy einsum k=4: separately-rounded products,
// pairwise association, fp contract OFF (bit-exact winner selection).
// ---------------------------------------------------------------------------
__global__ __launch_bounds__(BLK) void k_bin(
        const float* __restrict__ pc,   // (B,N,3)
        const float* __restrict__ tm,   // (B,3,4)
        unsigned int* __restrict__ arena,
        unsigned int* __restrict__ toff,
        unsigned int* __restrict__ tcnt,
        int* __restrict__ sbdump)
{
#pragma clang fp contract(off)
    const int b   = blockIdx.y;
    const int tid = threadIdx.x;
    const int gg  = b * NBLK + blockIdx.x;

    __shared__ int sb[BORD];
    __shared__ unsigned int hist[NBAND];
    __shared__ unsigned int lofs[NBAND];
    for (int k = tid; k < BORD; k += BLK) sb[k] = -1;
    if (tid < NBAND) hist[tid] = 0u;
    __syncthreads();

    const float* M = tm + b * 12;
    const float m0 = M[0], m1 = M[1], m2 = M[2], m3 = M[3];
    const float m4 = M[4], m5 = M[5], m6 = M[6], m7 = M[7];

    unsigned int ent[PPT], rb[PPT];
    const int base = blockIdx.x * BPB + tid;

    #pragma unroll
    for (int k = 0; k < PPT; ++k) {
        rb[k] = 0xFFFFFFFFu;
        int n = base + k * BLK;
        if (n < NPTS) {
            const float* p = pc + ((size_t)b * NPTS + n) * 3;
            float x = p[0], y = p[1], z = p[2];
            float tx = (x * m0 + y * m1) + (z * m2 + m3);
            float ty = (x * m4 + y * m5) + (z * m6 + m7);
            float nx = tx * 0.5f;
            float ny = ty * 0.5f;
            float px = (nx + 1.0f) * 512.0f;
            float py = (1.0f - ny) * 512.0f;
            px = fminf(fmaxf(px, 0.0f), 1023.0f);
            py = fminf(fmaxf(py, 0.0f), 1023.0f);
            int xi = (int)floorf(px);
            int yi = (int)floorf(py);

            bool border = (xi == 0) | (xi == 1023) | (yi == 0) | (yi == 1023);
            if (border) {
                int idx = (yi == 0)    ? xi
                        : (yi == 1023) ? 1024 + xi
                        : (xi == 0)    ? 2048 + yi
                                       : 3072 + yi;
                atomicMax(&sb[idx], n);
            } else {
                int bin = yi >> 4;
                unsigned r = atomicAdd(&hist[bin], 1u);     // local rank
                rb[k]  = ((unsigned)bin << 12) | r;          // r <= 4095
                ent[k] = ((unsigned)((yi & 15) * RES + xi) << 18) | (unsigned)n;
            }
        }
    }
    __syncthreads();

    // wave 0 (tid<64): exclusive scan of hist -> lofs; export offsets/counts
    if (tid < NBAND) {
        unsigned v = hist[tid];
        unsigned s = v;
        #pragma unroll
        for (int d = 1; d < 64; d <<= 1) {
            unsigned o = __shfl_up(s, d);
            if (tid >= d) s += o;
        }
        unsigned excl = s - v;
        lofs[tid] = excl;
        toff[gg * NBAND + tid] = (unsigned)gg * BPB + excl;
        tcnt[gg * NBAND + tid] = v;
    }
    __syncthreads();

    #pragma unroll
    for (int k = 0; k < PPT; ++k) {
        if (rb[k] != 0xFFFFFFFFu) {
            unsigned bin = rb[k] >> 12, r = rb[k] & 4095u;
            arena[(size_t)gg * BPB + lofs[bin] + r] = ent[k];
        }
    }

    // dump border LDS array (coalesced, no atomics)
    for (int k = tid; k < BORD; k += BLK)
        sbdump[(size_t)gg * BORD + k] = sb[k];
}

// ---------------------------------------------------------------------------
// Pass 2: merge the 49 per-block border dumps -> bwin[b][4096]. No atomics.
// ---------------------------------------------------------------------------
__global__ __launch_bounds__(256) void k_merge(
        const int* __restrict__ sbdump,
        int* __restrict__ bwin)
{
    int j = blockIdx.x * 256 + threadIdx.x;   // 0 .. NB*BORD-1
    int b = j >> 12, s = j & 4095;
    int m = -1;
    for (int g = 0; g < NBLK; ++g)
        m = max(m, sbdump[((size_t)(b * NBLK + g) << 12) + s]);
    bwin[j] = m;
}

// ---------------------------------------------------------------------------
// Pass 3: one block per (batch, band). 64KB LDS winner tile, DS atomicMax,
// then write final z directly (border pixels merge bwin). No global atomics.
// ---------------------------------------------------------------------------
__global__ __launch_bounds__(1024) void k_tile(
        const unsigned int* __restrict__ arena,
        const unsigned int* __restrict__ toff,
        const unsigned int* __restrict__ tcnt,
        const int* __restrict__ bwin,
        const float* __restrict__ pc,
        const float* __restrict__ tm,
        float* __restrict__ out)
{
#pragma clang fp contract(off)
    const int bucket = blockIdx.x;        // 0 .. NB*NBAND-1
    const int b = bucket >> 6, band = bucket & 63;
    const int tid = threadIdx.x;

    __shared__ int tile[BANDH * RES];     // 65536 B
    for (int k = tid; k < BANDH * RES; k += 1024) tile[k] = -1;
    __syncthreads();

    const int wave = tid >> 6, lane = tid & 63;
    for (int g = wave; g < NBLK; g += 16) {
        const int gg = b * NBLK + g;
        unsigned off = toff[gg * NBAND + band];
        unsigned cnt = tcnt[gg * NBAND + band];
        for (unsigned j = lane; j < cnt; j += 64) {
            unsigned e = arena[off + j];
            atomicMax(&tile[e >> 18], (int)(e & 0x3FFFFu));
        }
    }
    __syncthreads();

    const float* M2 = tm + b * 12 + 8;
    const float m8 = M2[0], m9 = M2[1], m10 = M2[2], m11 = M2[3];
    const int y0 = band * BANDH;
    const int* bw = bwin + b * BORD;

    for (int r = 0; r < BANDH; ++r) {     // 1024 threads = one full row
        int xi = tid;
        int yi = y0 + r;
        int n = tile[r * RES + xi];
        if (yi == 0)         n = max(n, bw[xi]);
        else if (yi == 1023) n = max(n, bw[1024 + xi]);
        if (xi == 0)         n = max(n, bw[2048 + yi]);
        else if (xi == 1023) n = max(n, bw[3072 + yi]);

        float zv = 0.0f;
        if (n >= 0) {
            const float* p = pc + ((size_t)b * NPTS + n) * 3;
            float t = (p[0] * m8 + p[1] * m9) + (p[2] * m10 + m11);
            zv = t * 0.5f;
        }
        out[((size_t)b * RES + yi) * RES + xi] = zv;
    }
}

// ---------------------------------------------------------------------------
extern "C" void kernel_launch(void* const* d_in, const int* in_sizes, int n_in,
                              void* d_out, int out_size, void* d_ws, size_t ws_size,
                              hipStream_t stream)
{
    const float* pc = (const float*)d_in[0];   // (32,200000,3) f32
    const float* tm = (const float*)d_in[1];   // (32,3,4) f32
    float* out = (float*)d_out;                // (32,1024,1024) f32

    char* ws = (char*)d_ws;
    unsigned int* arena  = (unsigned int*)(ws + OFF_AR);
    unsigned int* toff   = (unsigned int*)(ws + OFF_TO);
    unsigned int* tcnt   = (unsigned int*)(ws + OFF_TC);
    int*          sbdump = (int*)        (ws + OFF_SB);
    int*          bwin   = (int*)        (ws + OFF_BW);

    dim3 g1(NBLK, NB);
    k_bin<<<g1, BLK, 0, stream>>>(pc, tm, arena, toff, tcnt, sbdump);

    k_merge<<<(NB * BORD) / 256, 256, 0, stream>>>(sbdump, bwin);

    k_tile<<<NB * NBAND, 1024, 0, stream>>>(arena, toff, tcnt, bwin, pc, tm, out);
}

// Round 7
// 119.188 us; speedup vs baseline: 13.4784x; 1.0510x over previous
//
#include <hip/hip_runtime.h>

#define RES   1024
#define NPTS  200000
#define NB    32
#define PPT   16
#define BLK   256
#define NBLK  49          // blocks per batch = ceil(200000/4096)
#define BPB   (BLK*PPT)   // 4096 points per block
#define NBAND 128         // 128 bands of 8 rows
#define BANDH 8
#define BORD  4096        // 4*1024 border pixels

// ws layout:
//  arena : NB*NBLK*BPB u64   = 51,380,224 B
//  toff  : NB*NBLK*NBAND u32 =    802,816 B
//  tcnt  : NB*NBLK*NBAND u32 =    802,816 B
//  sbdump: NB*NBLK*BORD i32  = 25,690,112 B
//  bwin  : NB*BORD i32       =    524,288 B   (total ~79.2 MB)
#define OFF_AR 0
#define OFF_TO 51380224
#define OFF_TC 52183040
#define OFF_SB 52985856
#define OFF_BW 78675968

// ---------------------------------------------------------------------------
// Pass 1: bin points. Interior -> banded arena of u64 entries
//   pix(13b)<<50 | n(18b)<<32 | zbits(32b)
// so the resolve never touches the point cloud again. Border -> LDS sb[4096],
// dumped coalesced. ZERO global atomics. Dot products replicate numpy einsum
// k=4: separately-rounded products, pairwise association, fp contract OFF.
// ---------------------------------------------------------------------------
__global__ __launch_bounds__(BLK) void k_bin(
        const float* __restrict__ pc,   // (B,N,3)
        const float* __restrict__ tm,   // (B,3,4)
        unsigned long long* __restrict__ arena,
        unsigned int* __restrict__ toff,
        unsigned int* __restrict__ tcnt,
        int* __restrict__ sbdump)
{
#pragma clang fp contract(off)
    const int b   = blockIdx.y;
    const int tid = threadIdx.x;
    const int gg  = b * NBLK + blockIdx.x;

    __shared__ int sb[BORD];
    __shared__ unsigned int hist[NBAND];
    __shared__ unsigned int lofs[NBAND];
    __shared__ unsigned int wsum;
    for (int k = tid; k < BORD; k += BLK) sb[k] = -1;
    if (tid < NBAND) hist[tid] = 0u;
    __syncthreads();

    const float* M = tm + b * 12;
    const float m0 = M[0], m1 = M[1], m2  = M[2],  m3  = M[3];
    const float m4 = M[4], m5 = M[5], m6  = M[6],  m7  = M[7];
    const float m8 = M[8], m9 = M[9], m10 = M[10], m11 = M[11];

    unsigned long long ent[PPT];
    unsigned int rb[PPT];
    const int base = blockIdx.x * BPB + tid;

    #pragma unroll
    for (int k = 0; k < PPT; ++k) {
        rb[k] = 0xFFFFFFFFu;
        int n = base + k * BLK;
        if (n < NPTS) {
            const float* p = pc + ((size_t)b * NPTS + n) * 3;
            float x = p[0], y = p[1], z = p[2];
            float tx = (x * m0 + y * m1) + (z * m2  + m3);
            float ty = (x * m4 + y * m5) + (z * m6  + m7);
            float tz = (x * m8 + y * m9) + (z * m10 + m11);
            float nx = tx * 0.5f;
            float ny = ty * 0.5f;
            float nz = tz * 0.5f;
            float px = (nx + 1.0f) * 512.0f;
            float py = (1.0f - ny) * 512.0f;
            px = fminf(fmaxf(px, 0.0f), 1023.0f);
            py = fminf(fmaxf(py, 0.0f), 1023.0f);
            int xi = (int)floorf(px);
            int yi = (int)floorf(py);

            bool border = (xi == 0) | (xi == 1023) | (yi == 0) | (yi == 1023);
            if (border) {
                int idx = (yi == 0)    ? xi
                        : (yi == 1023) ? 1024 + xi
                        : (xi == 0)    ? 2048 + yi
                                       : 3072 + yi;
                atomicMax(&sb[idx], n);
            } else {
                int bin = yi >> 3;                       // 8-row bands
                unsigned r = atomicAdd(&hist[bin], 1u);  // local rank
                rb[k] = ((unsigned)bin << 12) | r;       // r <= 4095
                unsigned pix = (unsigned)((yi & 7) * RES + xi);   // 13 bits
                ent[k] = ((unsigned long long)pix << 50)
                       | ((unsigned long long)(unsigned)n << 32)
                       | (unsigned long long)__float_as_uint(nz);
            }
        }
    }
    __syncthreads();

    // exclusive scan of hist[128] across two waves
    if (tid < NBAND) {
        unsigned v = hist[tid];
        unsigned s = v;
        #pragma unroll
        for (int d = 1; d < 64; d <<= 1) {
            unsigned o = __shfl_up(s, d);
            if ((tid & 63) >= d) s += o;
        }
        lofs[tid] = s - v;           // exclusive within wave
        if (tid == 63) wsum = s;     // wave-0 total
    }
    __syncthreads();
    if (tid >= 64 && tid < NBAND) lofs[tid] += wsum;
    __syncthreads();
    if (tid < NBAND) {
        toff[gg * NBAND + tid] = (unsigned)gg * BPB + lofs[tid];
        tcnt[gg * NBAND + tid] = hist[tid];
    }
    __syncthreads();

    #pragma unroll
    for (int k = 0; k < PPT; ++k) {
        if (rb[k] != 0xFFFFFFFFu) {
            unsigned bin = rb[k] >> 12, r = rb[k] & 4095u;
            arena[(size_t)gg * BPB + lofs[bin] + r] = ent[k];
        }
    }

    for (int k = tid; k < BORD; k += BLK)
        sbdump[(size_t)gg * BORD + k] = sb[k];
}

// ---------------------------------------------------------------------------
// Pass 2: merge the 49 per-block border dumps -> bwin[b][4096]. No atomics.
// ---------------------------------------------------------------------------
__global__ __launch_bounds__(256) void k_merge(
        const int* __restrict__ sbdump,
        int* __restrict__ bwin)
{
    int j = blockIdx.x * 256 + threadIdx.x;   // 0 .. NB*BORD-1
    int b = j >> 12, s = j & 4095;
    int m = -1;
    for (int g = 0; g < NBLK; ++g)
        m = max(m, sbdump[((size_t)(b * NBLK + g) << 12) + s]);
    bwin[j] = m;
}

// ---------------------------------------------------------------------------
// Pass 3: one block per (batch, 8-row band). u64 LDS z-tile (64 KB):
// atomicMax on key = n<<32 | zbits -> winner's z is the low word. Interior
// pixels need NO point-cloud gather; border pixels (disjoint) use bwin + a
// tiny gather.
// ---------------------------------------------------------------------------
__global__ __launch_bounds__(1024) void k_tile(
        const unsigned long long* __restrict__ arena,
        const unsigned int* __restrict__ toff,
        const unsigned int* __restrict__ tcnt,
        const int* __restrict__ bwin,
        const float* __restrict__ pc,
        const float* __restrict__ tm,
        float* __restrict__ out)
{
#pragma clang fp contract(off)
    const int bucket = blockIdx.x;            // 0 .. NB*NBAND-1
    const int b = bucket >> 7, band = bucket & 127;
    const int tid = threadIdx.x;

    __shared__ unsigned long long tile[BANDH * RES];   // 65536 B
    for (int k = tid; k < BANDH * RES; k += 1024) tile[k] = 0ull;
    __syncthreads();

    const int wave = tid >> 6, lane = tid & 63;
    for (int g = wave; g < NBLK; g += 16) {
        const int gg = b * NBLK + g;
        unsigned off = toff[gg * NBAND + band];
        unsigned cnt = tcnt[gg * NBAND + band];
        for (unsigned j = lane; j < cnt; j += 64) {
            unsigned long long e = arena[off + j];
            atomicMax(&tile[e >> 50], e & 0x0003FFFFFFFFFFFFull);
        }
    }
    __syncthreads();

    const float* M2 = tm + b * 12 + 8;
    const float m8 = M2[0], m9 = M2[1], m10 = M2[2], m11 = M2[3];
    const int y0 = band * BANDH;
    const int* bw = bwin + b * BORD;

    for (int r = 0; r < BANDH; ++r) {
        int xi = tid;
        int yi = y0 + r;
        float zv;
        bool isb = (yi == 0) | (yi == 1023) | (xi == 0) | (xi == 1023);
        if (isb) {
            int n = (yi == 0)    ? bw[xi]
                  : (yi == 1023) ? bw[1024 + xi]
                  : (xi == 0)    ? bw[2048 + yi]
                                 : bw[3072 + yi];
            zv = 0.0f;
            if (n >= 0) {
                const float* p = pc + ((size_t)b * NPTS + n) * 3;
                float t = (p[0] * m8 + p[1] * m9) + (p[2] * m10 + m11);
                zv = t * 0.5f;
            }
        } else {
            unsigned long long key = tile[r * RES + xi];
            zv = __uint_as_float((unsigned)(key & 0xFFFFFFFFull));
        }
        out[((size_t)b * RES + yi) * RES + xi] = zv;
    }
}

// ---------------------------------------------------------------------------
extern "C" void kernel_launch(void* const* d_in, const int* in_sizes, int n_in,
                              void* d_out, int out_size, void* d_ws, size_t ws_size,
                              hipStream_t stream)
{
    const float* pc = (const float*)d_in[0];   // (32,200000,3) f32
    const float* tm = (const float*)d_in[1];   // (32,3,4) f32
    float* out = (float*)d_out;                // (32,1024,1024) f32

    char* ws = (char*)d_ws;
    unsigned long long* arena = (unsigned long long*)(ws + OFF_AR);
    unsigned int* toff   = (unsigned int*)(ws + OFF_TO);
    unsigned int* tcnt   = (unsigned int*)(ws + OFF_TC);
    int*          sbdump = (int*)        (ws + OFF_SB);
    int*          bwin   = (int*)        (ws + OFF_BW);

    dim3 g1(NBLK, NB);
    k_bin<<<g1, BLK, 0, stream>>>(pc, tm, arena, toff, tcnt, sbdump);

    k_merge<<<(NB * BORD) / 256, 256, 0, stream>>>(sbdump, bwin);

    k_tile<<<NB * NBAND, 1024, 0, stream>>>(arena, toff, tcnt, bwin, pc, tm, out);
}

// Round 8
// 102.700 us; speedup vs baseline: 15.6423x; 1.1605x over previous
//
#include <hip/hip_runtime.h>

#define RES   1024
#define NPTS  200000
#define NB    32
#define PPT   16
#define BLK   256
#define NBLK  49          // blocks per batch = ceil(200000/4096)
#define BPB   (BLK*PPT)   // 4096 points per block
#define NBAND 256         // 256 bands of 4 rows
#define BANDH 4
#define BORD  4096        // 4*1024 border pixels

// ws layout:
//  arena : NB*NBLK*BPB u64   = 51,380,224 B
//  toff  : NB*NBLK*NBAND u32 =  1,605,632 B
//  tcnt  : NB*NBLK*NBAND u32 =  1,605,632 B
//  bwin  : NB*BORD i32       =    524,288 B   (total ~55.1 MB)
#define OFF_AR 0
#define OFF_TO 51380224
#define OFF_TC 52985856
#define OFF_BW 54591488

// ---------------------------------------------------------------------------
// Pass 1: bin points. Interior -> banded arena of u64 entries
//   pix(12b)<<52 | n(18b)<<32 | zbits(32b)
// (resolve never touches the point cloud). Border -> LDS sb[4096], flushed
// with global atomicMax to bwin (<=49 contenders/address, ~68K atomics).
// Dot products replicate numpy einsum k=4: separately-rounded products,
// pairwise association, fp contract OFF (bit-exact winner selection).
// ---------------------------------------------------------------------------
__global__ __launch_bounds__(BLK) void k_bin(
        const float* __restrict__ pc,   // (B,N,3)
        const float* __restrict__ tm,   // (B,3,4)
        unsigned long long* __restrict__ arena,
        unsigned int* __restrict__ toff,
        unsigned int* __restrict__ tcnt,
        int* __restrict__ bwin)         // (B,4096) init -1
{
#pragma clang fp contract(off)
    const int b   = blockIdx.y;
    const int tid = threadIdx.x;
    const int gg  = b * NBLK + blockIdx.x;

    __shared__ int sb[BORD];
    __shared__ unsigned int hist[NBAND];
    __shared__ unsigned int lofs[NBAND];
    for (int k = tid; k < BORD; k += BLK) sb[k] = -1;
    hist[tid] = 0u;                      // BLK == NBAND == 256
    __syncthreads();

    const float* M = tm + b * 12;
    const float m0 = M[0], m1 = M[1], m2  = M[2],  m3  = M[3];
    const float m4 = M[4], m5 = M[5], m6  = M[6],  m7  = M[7];
    const float m8 = M[8], m9 = M[9], m10 = M[10], m11 = M[11];

    unsigned long long ent[PPT];
    unsigned int rb[PPT];
    const int base = blockIdx.x * BPB + tid;

    #pragma unroll
    for (int k = 0; k < PPT; ++k) {
        rb[k] = 0xFFFFFFFFu;
        int n = base + k * BLK;
        if (n < NPTS) {
            const float* p = pc + ((size_t)b * NPTS + n) * 3;
            float x = p[0], y = p[1], z = p[2];
            float tx = (x * m0 + y * m1) + (z * m2  + m3);
            float ty = (x * m4 + y * m5) + (z * m6  + m7);
            float tz = (x * m8 + y * m9) + (z * m10 + m11);
            float nx = tx * 0.5f;
            float ny = ty * 0.5f;
            float nz = tz * 0.5f;
            float px = (nx + 1.0f) * 512.0f;
            float py = (1.0f - ny) * 512.0f;
            px = fminf(fmaxf(px, 0.0f), 1023.0f);
            py = fminf(fmaxf(py, 0.0f), 1023.0f);
            int xi = (int)floorf(px);
            int yi = (int)floorf(py);

            bool border = (xi == 0) | (xi == 1023) | (yi == 0) | (yi == 1023);
            if (border) {
                int idx = (yi == 0)    ? xi
                        : (yi == 1023) ? 1024 + xi
                        : (xi == 0)    ? 2048 + yi
                                       : 3072 + yi;
                atomicMax(&sb[idx], n);
            } else {
                int bin = yi >> 2;                       // 4-row bands
                unsigned r = atomicAdd(&hist[bin], 1u);  // local rank
                rb[k] = ((unsigned)bin << 12) | r;       // r <= 4095
                unsigned pix = (unsigned)((yi & 3) * RES + xi);   // 12 bits
                ent[k] = ((unsigned long long)pix << 52)
                       | ((unsigned long long)(unsigned)n << 32)
                       | (unsigned long long)__float_as_uint(nz);
            }
        }
    }
    __syncthreads();

    // exclusive scan of hist[256]: wave 0, 4 chunks of 64 with carry
    if (tid < 64) {
        unsigned carry = 0;
        #pragma unroll
        for (int c = 0; c < 4; ++c) {
            unsigned v = hist[c * 64 + tid];
            unsigned s = v;
            #pragma unroll
            for (int d = 1; d < 64; d <<= 1) {
                unsigned o = __shfl_up(s, d);
                if (tid >= d) s += o;
            }
            lofs[c * 64 + tid] = (s - v) + carry;
            carry += __shfl(s, 63);
        }
    }
    __syncthreads();

    toff[gg * NBAND + tid] = (unsigned)gg * BPB + lofs[tid];
    tcnt[gg * NBAND + tid] = hist[tid];

    #pragma unroll
    for (int k = 0; k < PPT; ++k) {
        if (rb[k] != 0xFFFFFFFFu) {
            unsigned bin = rb[k] >> 12, r = rb[k] & 4095u;
            arena[(size_t)gg * BPB + lofs[bin] + r] = ent[k];
        }
    }

    // flush occupied border entries straight to bwin (bounded contention)
    for (int k = tid; k < BORD; k += BLK) {
        int v = sb[k];
        if (v >= 0) atomicMax(&bwin[b * BORD + k], v);
    }
}

// ---------------------------------------------------------------------------
// Pass 2: one block per (batch, 4-row band). 512 threads, 32 KB u64 LDS tile
// -> 4 blocks/CU (100% thread-limit occupancy). toff/tcnt for all 49 source
// blocks preloaded into LDS (no dependent scalar-load chains in the g-loop).
// atomicMax key = n<<32 | zbits; winner's z is the low word. Border pixels
// (disjoint from interior) resolve from bwin + tiny gather.
// ---------------------------------------------------------------------------
__global__ __launch_bounds__(512) void k_tile(
        const unsigned long long* __restrict__ arena,
        const unsigned int* __restrict__ toff,
        const unsigned int* __restrict__ tcnt,
        const int* __restrict__ bwin,
        const float* __restrict__ pc,
        const float* __restrict__ tm,
        float* __restrict__ out)
{
#pragma clang fp contract(off)
    const int bucket = blockIdx.x;            // 0 .. NB*NBAND-1
    const int b = bucket >> 8, band = bucket & 255;
    const int tid = threadIdx.x;

    __shared__ unsigned long long tile[BANDH * RES];   // 32768 B
    __shared__ unsigned int stoff[NBLK], scnt[NBLK];
    for (int k = tid; k < BANDH * RES; k += 512) tile[k] = 0ull;
    if (tid < NBLK) {
        stoff[tid] = toff[(b * NBLK + tid) * NBAND + band];
        scnt[tid]  = tcnt[(b * NBLK + tid) * NBAND + band];
    }
    __syncthreads();

    const int wave = tid >> 6, lane = tid & 63;
    for (int g = wave; g < NBLK; g += 8) {
        unsigned off = stoff[g], cnt = scnt[g];
        for (unsigned j = lane; j < cnt; j += 64) {
            unsigned long long e = arena[off + j];
            atomicMax(&tile[e >> 52], e & 0x000FFFFFFFFFFFFFull);
        }
    }
    __syncthreads();

    const float* M2 = tm + b * 12 + 8;
    const float m8 = M2[0], m9 = M2[1], m10 = M2[2], m11 = M2[3];
    const int y0 = band * BANDH;
    const int* bw = bwin + b * BORD;

    for (int r = 0; r < BANDH; ++r) {
        int yi = y0 + r;
        float2 o2;
        #pragma unroll
        for (int h = 0; h < 2; ++h) {
            int xi = tid * 2 + h;
            float zv;
            bool isb = (yi == 0) | (yi == 1023) | (xi == 0) | (xi == 1023);
            if (isb) {
                int n = (yi == 0)    ? bw[xi]
                      : (yi == 1023) ? bw[1024 + xi]
                      : (xi == 0)    ? bw[2048 + yi]
                                     : bw[3072 + yi];
                zv = 0.0f;
                if (n >= 0) {
                    const float* p = pc + ((size_t)b * NPTS + n) * 3;
                    float t = (p[0] * m8 + p[1] * m9) + (p[2] * m10 + m11);
                    zv = t * 0.5f;
                }
            } else {
                zv = __uint_as_float((unsigned)(tile[r * RES + xi] & 0xFFFFFFFFull));
            }
            if (h) o2.y = zv; else o2.x = zv;
        }
        ((float2*)(out + ((size_t)b * RES + yi) * RES))[tid] = o2;
    }
}

// ---------------------------------------------------------------------------
extern "C" void kernel_launch(void* const* d_in, const int* in_sizes, int n_in,
                              void* d_out, int out_size, void* d_ws, size_t ws_size,
                              hipStream_t stream)
{
    const float* pc = (const float*)d_in[0];   // (32,200000,3) f32
    const float* tm = (const float*)d_in[1];   // (32,3,4) f32
    float* out = (float*)d_out;                // (32,1024,1024) f32

    char* ws = (char*)d_ws;
    unsigned long long* arena = (unsigned long long*)(ws + OFF_AR);
    unsigned int* toff = (unsigned int*)(ws + OFF_TO);
    unsigned int* tcnt = (unsigned int*)(ws + OFF_TC);
    int*          bwin = (int*)         (ws + OFF_BW);

    hipMemsetAsync(bwin, 0xFF, (size_t)NB * BORD * sizeof(int), stream);

    dim3 g1(NBLK, NB);
    k_bin<<<g1, BLK, 0, stream>>>(pc, tm, arena, toff, tcnt, bwin);

    k_tile<<<NB * NBAND, 512, 0, stream>>>(arena, toff, tcnt, bwin, pc, tm, out);
}

// Round 9
// 91.972 us; speedup vs baseline: 17.4669x; 1.1166x over previous
//
#include <hip/hip_runtime.h>

#define RES   1024
#define NPTS  200000
#define NB    32
#define PPT   16
#define BLK   256
#define NBLK  49          // blocks per batch = ceil(200000/4096)
#define BPB   (BLK*PPT)   // 4096 points per block
#define NBAND 256         // 256 bands of 4 rows
#define BANDH 4
#define BORD  4096        // 4*1024 border pixels

// ws layout:
//  arena : NB*NBLK*BPB u64          = 51,380,224 B
//  tmeta : NB*NBAND*NBLK u32        =  1,605,632 B   (lofs<<16 | cnt, band-major)
//  bwin  : NB*BORD i32              =    524,288 B   (total ~53.5 MB)
#define OFF_AR 0
#define OFF_TM 51380224
#define OFF_BW 52985856

// ---------------------------------------------------------------------------
// Pass 0: init border-winner buffer to -1 (replaces opaque rocclr fill).
// ---------------------------------------------------------------------------
__global__ __launch_bounds__(256) void k_init(int4* __restrict__ bwin4)
{
    int i = blockIdx.x * 256 + threadIdx.x;          // 32768 int4 = 131072 ints
    bwin4[i] = make_int4(-1, -1, -1, -1);
}

// ---------------------------------------------------------------------------
// Pass 1: bin points. Interior -> banded arena of u64 entries
//   pix(12b)<<52 | n(18b)<<32 | zbits(32b)
// Border -> LDS sb[4096], flushed with global atomicMax to bwin (<=49
// contenders/address). tmeta written band-major so k_tile reads 49
// consecutive words. Dot products replicate numpy einsum k=4:
// separately-rounded products, pairwise association, fp contract OFF.
// ---------------------------------------------------------------------------
__global__ __launch_bounds__(BLK) void k_bin(
        const float* __restrict__ pc,   // (B,N,3)
        const float* __restrict__ tm,   // (B,3,4)
        unsigned long long* __restrict__ arena,
        unsigned int* __restrict__ tmeta,
        int* __restrict__ bwin)         // (B,4096) init -1
{
#pragma clang fp contract(off)
    const int b   = blockIdx.y;
    const int tid = threadIdx.x;
    const int gg  = b * NBLK + blockIdx.x;

    __shared__ int sb[BORD];
    __shared__ unsigned int hist[NBAND];
    __shared__ unsigned int lofs[NBAND];
    for (int k = tid; k < BORD; k += BLK) sb[k] = -1;
    hist[tid] = 0u;                      // BLK == NBAND == 256
    __syncthreads();

    const float* M = tm + b * 12;
    const float m0 = M[0], m1 = M[1], m2  = M[2],  m3  = M[3];
    const float m4 = M[4], m5 = M[5], m6  = M[6],  m7  = M[7];
    const float m8 = M[8], m9 = M[9], m10 = M[10], m11 = M[11];

    unsigned long long ent[PPT];
    unsigned int rb[PPT];
    const int base = blockIdx.x * BPB + tid;

    #pragma unroll
    for (int k = 0; k < PPT; ++k) {
        rb[k] = 0xFFFFFFFFu;
        int n = base + k * BLK;
        if (n < NPTS) {
            const float* p = pc + ((size_t)b * NPTS + n) * 3;
            float x = p[0], y = p[1], z = p[2];
            float tx = (x * m0 + y * m1) + (z * m2  + m3);
            float ty = (x * m4 + y * m5) + (z * m6  + m7);
            float tz = (x * m8 + y * m9) + (z * m10 + m11);
            float nx = tx * 0.5f;
            float ny = ty * 0.5f;
            float nz = tz * 0.5f;
            float px = (nx + 1.0f) * 512.0f;
            float py = (1.0f - ny) * 512.0f;
            px = fminf(fmaxf(px, 0.0f), 1023.0f);
            py = fminf(fmaxf(py, 0.0f), 1023.0f);
            int xi = (int)floorf(px);
            int yi = (int)floorf(py);

            bool border = (xi == 0) | (xi == 1023) | (yi == 0) | (yi == 1023);
            if (border) {
                int idx = (yi == 0)    ? xi
                        : (yi == 1023) ? 1024 + xi
                        : (xi == 0)    ? 2048 + yi
                                       : 3072 + yi;
                atomicMax(&sb[idx], n);
            } else {
                int bin = yi >> 2;                       // 4-row bands
                unsigned r = atomicAdd(&hist[bin], 1u);  // local rank
                rb[k] = ((unsigned)bin << 12) | r;       // r <= 4095
                unsigned pix = (unsigned)((yi & 3) * RES + xi);   // 12 bits
                ent[k] = ((unsigned long long)pix << 52)
                       | ((unsigned long long)(unsigned)n << 32)
                       | (unsigned long long)__float_as_uint(nz);
            }
        }
    }
    __syncthreads();

    // exclusive scan of hist[256]: wave 0, 4 chunks of 64 with carry
    if (tid < 64) {
        unsigned carry = 0;
        #pragma unroll
        for (int c = 0; c < 4; ++c) {
            unsigned v = hist[c * 64 + tid];
            unsigned s = v;
            #pragma unroll
            for (int d = 1; d < 64; d <<= 1) {
                unsigned o = __shfl_up(s, d);
                if (tid >= d) s += o;
            }
            lofs[c * 64 + tid] = (s - v) + carry;
            carry += __shfl(s, 63);
        }
    }
    __syncthreads();

    // band-major metadata: k_tile block (b,band) reads 49 consecutive words
    tmeta[((size_t)(b * NBAND + tid)) * NBLK + blockIdx.x]
        = (lofs[tid] << 16) | hist[tid];

    #pragma unroll
    for (int k = 0; k < PPT; ++k) {
        if (rb[k] != 0xFFFFFFFFu) {
            unsigned bin = rb[k] >> 12, r = rb[k] & 4095u;
            arena[(size_t)gg * BPB + lofs[bin] + r] = ent[k];
        }
    }

    // flush occupied border entries straight to bwin (bounded contention)
    for (int k = tid; k < BORD; k += BLK) {
        int v = sb[k];
        if (v >= 0) atomicMax(&bwin[b * BORD + k], v);
    }
}

// ---------------------------------------------------------------------------
// Pass 2: one block per (batch, 4-row band). 512 threads, 32 KB u64 LDS tile
// (4 blocks/CU). Metadata = 49 consecutive words -> wave-0 prefix scan ->
// FLAT cooperative accumulate: all lanes process dense idx<T with idx->seg
// via 6-step LDS binary search; arena reads coalesced. atomicMax key =
// n<<32|zbits; winner z = low word. Border pixels resolve from bwin.
// ---------------------------------------------------------------------------
__global__ __launch_bounds__(512) void k_tile(
        const unsigned long long* __restrict__ arena,
        const unsigned int* __restrict__ tmeta,
        const int* __restrict__ bwin,
        const float* __restrict__ pc,
        const float* __restrict__ tm,
        float* __restrict__ out)
{
#pragma clang fp contract(off)
    const int bucket = blockIdx.x;            // 0 .. NB*NBAND-1
    const int b = bucket >> 8, band = bucket & 255;
    const int tid = threadIdx.x;

    __shared__ __align__(16) unsigned long long tile[BANDH * RES];  // 32768 B
    __shared__ unsigned int pref[NBLK + 1];   // exclusive starts; pref[49] = T
    __shared__ unsigned int sbase[NBLK];      // arena element base per segment

    for (int k = tid; k < BANDH * RES; k += 512) tile[k] = 0ull;

    unsigned mv = 0;
    if (tid < NBLK)
        mv = tmeta[((size_t)(b * NBAND + band)) * NBLK + tid];
    if (tid < 64) {
        unsigned cnt = (tid < NBLK) ? (mv & 0xFFFFu) : 0u;
        unsigned s = cnt;
        #pragma unroll
        for (int d = 1; d < 64; d <<= 1) {
            unsigned o = __shfl_up(s, d);
            if (tid >= d) s += o;
        }
        if (tid < NBLK) {
            pref[tid + 1] = s;                          // inclusive -> pref[g+1]
            sbase[tid] = (unsigned)((b * NBLK + tid) * BPB) + (mv >> 16);
        }
        if (tid == 0) pref[0] = 0u;
    }
    __syncthreads();

    const unsigned T = pref[NBLK];
    for (unsigned idx = tid; idx < T; idx += 512) {
        int lo = 0, hi = NBLK - 1;
        #pragma unroll
        for (int it = 0; it < 6; ++it) {                // ceil(log2(49)) = 6
            int mid = (lo + hi + 1) >> 1;
            if (pref[mid] <= idx) lo = mid; else hi = mid - 1;
        }
        unsigned long long e = arena[(size_t)sbase[lo] + (idx - pref[lo])];
        atomicMax(&tile[e >> 52], e & 0x000FFFFFFFFFFFFFull);
    }
    __syncthreads();

    const float* M2 = tm + b * 12 + 8;
    const float m8 = M2[0], m9 = M2[1], m10 = M2[2], m11 = M2[3];
    const int y0 = band * BANDH;
    const int* bw = bwin + b * BORD;

    for (int r = 0; r < BANDH; ++r) {
        int yi = y0 + r;
        ulonglong2 kk = ((const ulonglong2*)(tile + r * RES))[tid];
        float2 o2;
        o2.x = __uint_as_float((unsigned)(kk.x & 0xFFFFFFFFull));
        o2.y = __uint_as_float((unsigned)(kk.y & 0xFFFFFFFFull));

        #pragma unroll
        for (int h = 0; h < 2; ++h) {
            int xi = tid * 2 + h;
            bool isb = (yi == 0) | (yi == 1023) | (xi == 0) | (xi == 1023);
            if (isb) {
                int n = (yi == 0)    ? bw[xi]
                      : (yi == 1023) ? bw[1024 + xi]
                      : (xi == 0)    ? bw[2048 + yi]
                                     : bw[3072 + yi];
                float zv = 0.0f;
                if (n >= 0) {
                    const float* p = pc + ((size_t)b * NPTS + n) * 3;
                    float t = (p[0] * m8 + p[1] * m9) + (p[2] * m10 + m11);
                    zv = t * 0.5f;
                }
                if (h) o2.y = zv; else o2.x = zv;
            }
        }
        ((float2*)(out + ((size_t)b * RES + yi) * RES))[tid] = o2;
    }
}

// ---------------------------------------------------------------------------
extern "C" void kernel_launch(void* const* d_in, const int* in_sizes, int n_in,
                              void* d_out, int out_size, void* d_ws, size_t ws_size,
                              hipStream_t stream)
{
    const float* pc = (const float*)d_in[0];   // (32,200000,3) f32
    const float* tm = (const float*)d_in[1];   // (32,3,4) f32
    float* out = (float*)d_out;                // (32,1024,1024) f32

    char* ws = (char*)d_ws;
    unsigned long long* arena = (unsigned long long*)(ws + OFF_AR);
    unsigned int* tmeta = (unsigned int*)(ws + OFF_TM);
    int*          bwin  = (int*)         (ws + OFF_BW);

    k_init<<<(NB * BORD / 4) / 256, 256, 0, stream>>>((int4*)bwin);

    dim3 g1(NBLK, NB);
    k_bin<<<g1, BLK, 0, stream>>>(pc, tm, arena, tmeta, bwin);

    k_tile<<<NB * NBAND, 512, 0, stream>>>(arena, tmeta, bwin, pc, tm, out);
}

// Round 10
// 84.853 us; speedup vs baseline: 18.9325x; 1.0839x over previous
//
#include <hip/hip_runtime.h>

#define RES   1024
#define NPTS  200000
#define NB    32
#define PPT   8
#define BLK   512
#define NBLK  49          // blocks per batch = ceil(200000/4096)
#define BPB   4096        // points per block
#define NBAND 256         // 256 bands of 4 rows
#define BANDH 4
#define BORD  4096        // 4*1024 border pixels

// ws layout:
//  arena : NB*NBLK*BPB u64   = 51,380,224 B
//  tmeta : NB*NBAND*NBLK u32 =  1,605,632 B   (lofs<<16 | cnt, band-major)
//  bwin  : NB*BORD i32       =    524,288 B
#define OFF_AR 0
#define OFF_TM 51380224
#define OFF_BW 52985856

// ---------------------------------------------------------------------------
// Pass 0: init border-winner buffer to -1.
// ---------------------------------------------------------------------------
__global__ __launch_bounds__(256) void k_init(int4* __restrict__ bwin4)
{
    int i = blockIdx.x * 256 + threadIdx.x;          // 32768 int4
    bwin4[i] = make_int4(-1, -1, -1, -1);
}

// ---------------------------------------------------------------------------
// Pass 1: bin points. Interior -> u64 entries pix(12b)<<52 | n(18b)<<32 | z
// staged DENSE in LDS, then dumped coalesced to the arena (kills the 8x
// store-transaction amplification of per-point scattered global stores).
// Border -> LDS sb[4096], flushed with global atomicMax to bwin.
// Dot products replicate numpy einsum k=4: separately-rounded products,
// pairwise association, fp contract OFF (bit-exact winner selection).
// ---------------------------------------------------------------------------
__global__ __launch_bounds__(BLK) void k_bin(
        const float* __restrict__ pc,   // (B,N,3)
        const float* __restrict__ tm,   // (B,3,4)
        unsigned long long* __restrict__ arena,
        unsigned int* __restrict__ tmeta,
        int* __restrict__ bwin)         // (B,4096) init -1
{
#pragma clang fp contract(off)
    const int b   = blockIdx.y;
    const int tid = threadIdx.x;
    const int gg  = b * NBLK + blockIdx.x;

    __shared__ int sb[BORD];                          // 16 KB
    __shared__ unsigned long long stage[BPB];         // 32 KB
    __shared__ unsigned int hist[NBAND];              // 1 KB
    __shared__ unsigned int lofs[NBAND];              // 1 KB
    for (int k = tid; k < BORD; k += BLK) sb[k] = -1;
    if (tid < NBAND) hist[tid] = 0u;
    __syncthreads();

    const float* M = tm + b * 12;
    const float m0 = M[0], m1 = M[1], m2  = M[2],  m3  = M[3];
    const float m4 = M[4], m5 = M[5], m6  = M[6],  m7  = M[7];
    const float m8 = M[8], m9 = M[9], m10 = M[10], m11 = M[11];

    unsigned long long ent[PPT];
    unsigned int rb[PPT];
    const int base = blockIdx.x * BPB + tid;

    #pragma unroll
    for (int k = 0; k < PPT; ++k) {
        rb[k] = 0xFFFFFFFFu;
        int n = base + k * BLK;
        if (n < NPTS) {
            const float* p = pc + ((size_t)b * NPTS + n) * 3;
            float x = p[0], y = p[1], z = p[2];
            float tx = (x * m0 + y * m1) + (z * m2  + m3);
            float ty = (x * m4 + y * m5) + (z * m6  + m7);
            float tz = (x * m8 + y * m9) + (z * m10 + m11);
            float nx = tx * 0.5f;
            float ny = ty * 0.5f;
            float nz = tz * 0.5f;
            float px = (nx + 1.0f) * 512.0f;
            float py = (1.0f - ny) * 512.0f;
            px = fminf(fmaxf(px, 0.0f), 1023.0f);
            py = fminf(fmaxf(py, 0.0f), 1023.0f);
            int xi = (int)floorf(px);
            int yi = (int)floorf(py);

            bool border = (xi == 0) | (xi == 1023) | (yi == 0) | (yi == 1023);
            if (border) {
                int idx = (yi == 0)    ? xi
                        : (yi == 1023) ? 1024 + xi
                        : (xi == 0)    ? 2048 + yi
                                       : 3072 + yi;
                atomicMax(&sb[idx], n);
            } else {
                int bin = yi >> 2;                       // 4-row bands
                unsigned r = atomicAdd(&hist[bin], 1u);  // local rank
                rb[k] = ((unsigned)bin << 12) | r;       // r <= 4095
                unsigned pix = (unsigned)((yi & 3) * RES + xi);   // 12 bits
                ent[k] = ((unsigned long long)pix << 52)
                       | ((unsigned long long)(unsigned)n << 32)
                       | (unsigned long long)__float_as_uint(nz);
            }
        }
    }
    __syncthreads();

    // exclusive scan of hist[256]: wave 0, 4 chunks of 64 with carry
    if (tid < 64) {
        unsigned carry = 0;
        #pragma unroll
        for (int c = 0; c < 4; ++c) {
            unsigned v = hist[c * 64 + tid];
            unsigned s = v;
            #pragma unroll
            for (int d = 1; d < 64; d <<= 1) {
                unsigned o = __shfl_up(s, d);
                if (tid >= d) s += o;
            }
            lofs[c * 64 + tid] = (s - v) + carry;
            carry += __shfl(s, 63);
        }
    }
    __syncthreads();

    // band-major metadata: k_tile block (b,band) reads 49 consecutive words
    if (tid < NBAND)
        tmeta[((size_t)(b * NBAND + tid)) * NBLK + blockIdx.x]
            = (lofs[tid] << 16) | hist[tid];

    // stage entries dense in LDS at their final positions
    #pragma unroll
    for (int k = 0; k < PPT; ++k) {
        if (rb[k] != 0xFFFFFFFFu) {
            unsigned bin = rb[k] >> 12, r = rb[k] & 4095u;
            stage[lofs[bin] + r] = ent[k];
        }
    }
    __syncthreads();

    // coalesced dump of the dense prefix [0, Ttot)
    const unsigned Ttot = lofs[NBAND - 1] + hist[NBAND - 1];
    for (unsigned k = tid; k < Ttot; k += BLK)
        arena[(size_t)gg * BPB + k] = stage[k];

    // flush occupied border entries straight to bwin (bounded contention)
    for (int k = tid; k < BORD; k += BLK) {
        int v = sb[k];
        if (v >= 0) atomicMax(&bwin[b * BORD + k], v);
    }
}

// ---------------------------------------------------------------------------
// Pass 2: one block per (batch, 4-row band). 512 threads, 32 KB u64 LDS tile.
// Wave-0 prefix scan of the 49 segment counts -> flat cooperative accumulate
// (idx->seg via 6-step LDS binary search). atomicMax key = n<<32|zbits;
// winner z = low word. Border pixels resolve from bwin. (unchanged from r9)
// ---------------------------------------------------------------------------
__global__ __launch_bounds__(512) void k_tile(
        const unsigned long long* __restrict__ arena,
        const unsigned int* __restrict__ tmeta,
        const int* __restrict__ bwin,
        const float* __restrict__ pc,
        const float* __restrict__ tm,
        float* __restrict__ out)
{
#pragma clang fp contract(off)
    const int bucket = blockIdx.x;            // 0 .. NB*NBAND-1
    const int b = bucket >> 8, band = bucket & 255;
    const int tid = threadIdx.x;

    __shared__ __align__(16) unsigned long long tile[BANDH * RES];  // 32768 B
    __shared__ unsigned int pref[NBLK + 1];
    __shared__ unsigned int sbase[NBLK];

    for (int k = tid; k < BANDH * RES; k += 512) tile[k] = 0ull;

    unsigned mv = 0;
    if (tid < NBLK)
        mv = tmeta[((size_t)(b * NBAND + band)) * NBLK + tid];
    if (tid < 64) {
        unsigned cnt = (tid < NBLK) ? (mv & 0xFFFFu) : 0u;
        unsigned s = cnt;
        #pragma unroll
        for (int d = 1; d < 64; d <<= 1) {
            unsigned o = __shfl_up(s, d);
            if (tid >= d) s += o;
        }
        if (tid < NBLK) {
            pref[tid + 1] = s;
            sbase[tid] = (unsigned)((b * NBLK + tid) * BPB) + (mv >> 16);
        }
        if (tid == 0) pref[0] = 0u;
    }
    __syncthreads();

    const unsigned T = pref[NBLK];
    for (unsigned idx = tid; idx < T; idx += 512) {
        int lo = 0, hi = NBLK - 1;
        #pragma unroll
        for (int it = 0; it < 6; ++it) {                // ceil(log2(49)) = 6
            int mid = (lo + hi + 1) >> 1;
            if (pref[mid] <= idx) lo = mid; else hi = mid - 1;
        }
        unsigned long long e = arena[(size_t)sbase[lo] + (idx - pref[lo])];
        atomicMax(&tile[e >> 52], e & 0x000FFFFFFFFFFFFFull);
    }
    __syncthreads();

    const float* M2 = tm + b * 12 + 8;
    const float m8 = M2[0], m9 = M2[1], m10 = M2[2], m11 = M2[3];
    const int y0 = band * BANDH;
    const int* bw = bwin + b * BORD;

    for (int r = 0; r < BANDH; ++r) {
        int yi = y0 + r;
        ulonglong2 kk = ((const ulonglong2*)(tile + r * RES))[tid];
        float2 o2;
        o2.x = __uint_as_float((unsigned)(kk.x & 0xFFFFFFFFull));
        o2.y = __uint_as_float((unsigned)(kk.y & 0xFFFFFFFFull));

        #pragma unroll
        for (int h = 0; h < 2; ++h) {
            int xi = tid * 2 + h;
            bool isb = (yi == 0) | (yi == 1023) | (xi == 0) | (xi == 1023);
            if (isb) {
                int n = (yi == 0)    ? bw[xi]
                      : (yi == 1023) ? bw[1024 + xi]
                      : (xi == 0)    ? bw[2048 + yi]
                                     : bw[3072 + yi];
                float zv = 0.0f;
                if (n >= 0) {
                    const float* p = pc + ((size_t)b * NPTS + n) * 3;
                    float t = (p[0] * m8 + p[1] * m9) + (p[2] * m10 + m11);
                    zv = t * 0.5f;
                }
                if (h) o2.y = zv; else o2.x = zv;
            }
        }
        ((float2*)(out + ((size_t)b * RES + yi) * RES))[tid] = o2;
    }
}

// ---------------------------------------------------------------------------
extern "C" void kernel_launch(void* const* d_in, const int* in_sizes, int n_in,
                              void* d_out, int out_size, void* d_ws, size_t ws_size,
                              hipStream_t stream)
{
    const float* pc = (const float*)d_in[0];   // (32,200000,3) f32
    const float* tm = (const float*)d_in[1];   // (32,3,4) f32
    float* out = (float*)d_out;                // (32,1024,1024) f32

    char* ws = (char*)d_ws;
    unsigned long long* arena = (unsigned long long*)(ws + OFF_AR);
    unsigned int* tmeta = (unsigned int*)(ws + OFF_TM);
    int*          bwin  = (int*)         (ws + OFF_BW);

    k_init<<<(NB * BORD / 4) / 256, 256, 0, stream>>>((int4*)bwin);

    dim3 g1(NBLK, NB);
    k_bin<<<g1, BLK, 0, stream>>>(pc, tm, arena, tmeta, bwin);

    k_tile<<<NB * NBAND, 512, 0, stream>>>(arena, tmeta, bwin, pc, tm, out);
}